// Round 1
// baseline (506.028 us; speedup 1.0000x reference)
//
#include <hip/hip_runtime.h>

// MeanSpikeClassifier: interval-graph connected components.
// N = 96*96 = 9216 pixels, T = 64 steps, out = masks[N,N] ++ mean_grid[N] (f32).
//
// Key insight: adj(i,j) = (1 - |v_i - v_j| >= 0.6) is an interval graph on the
// value line. Components = maximal sorted runs not split by a "gap" (a value
// with no adjacent value above it). component_id(i) = #gap-start values < v_i.
// labels[i] = min pixel index in component (== reference's while_loop fixpoint).

#define N_PIX 9216

// K1: per-pixel mean of late steps; also init compmin / ngaps for later kernels
// (workspace is re-poisoned to 0xAA before every timed launch).
__global__ void k_means(const float* __restrict__ spike, const int* __restrict__ cs_p,
                        int T, float* __restrict__ v, float* __restrict__ out_grid,
                        int* __restrict__ compmin, int* __restrict__ ngaps) {
    int n = blockIdx.x * blockDim.x + threadIdx.x;
    if (n >= N_PIX) return;
    int cs = cs_p[0];
    int start = cs - 1;
    if (start < 0) start = 0;
    if (start > T - 1) start = T - 1;
    float s = 0.0f;
    for (int t = start; t < T; ++t)       // coalesced across n for each t
        s += spike[(size_t)t * N_PIX + n];
    float val = s / (float)(T - start);
    v[n] = val;
    out_grid[n] = val;
    compmin[n] = 0x7fffffff;
    if (n == 0) *ngaps = 0;
}

// K2: one block per pixel k — is k a "gap start"?
// gap(k) := (exists v_j > v_k) && (no j with v_j > v_k && 1-(v_j-v_k) >= 0.6f)
// Uses the EXACT float predicate of the reference (monotone in the diff).
__global__ void __launch_bounds__(256) k_gaps(const float* __restrict__ v,
                                              float* __restrict__ gaps,
                                              int* __restrict__ ngaps) {
    int k = blockIdx.x;
    float vk = v[k];
    int hasG = 0, hasAdj = 0;
    for (int j = threadIdx.x; j < N_PIX; j += 256) {
        float vj = v[j];                   // 36 KB array, L1/L2-resident
        if (vj > vk) {
            hasG = 1;
            if (1.0f - (vj - vk) >= 0.6f) hasAdj = 1;
        }
    }
    __shared__ int sG, sA;
    if (threadIdx.x == 0) { sG = 0; sA = 0; }
    __syncthreads();
    if (hasG)   atomicOr(&sG, 1);
    if (hasAdj) atomicOr(&sA, 1);
    __syncthreads();
    if (threadIdx.x == 0 && sG && !sA) {
        int idx = atomicAdd(ngaps, 1);     // order-independent downstream
        gaps[idx] = vk;
    }
}

// K3: component id = #gap values strictly below v_i (duplicates only shift ids,
// grouping stays consistent); record per-component min pixel index.
__global__ void k_ids(const float* __restrict__ v, const float* __restrict__ gaps,
                      const int* __restrict__ ngaps, int* __restrict__ gid,
                      int* __restrict__ compmin) {
    int i = blockIdx.x * blockDim.x + threadIdx.x;
    if (i >= N_PIX) return;
    float vi = v[i];
    int ng = *ngaps;                       // expected ~0-2 for this data
    int g = 0;
    for (int t = 0; t < ng; ++t) g += (gaps[t] < vi) ? 1 : 0;
    gid[i] = g;
    atomicMin(&compmin[g], i);
}

// K4: labels[i] = min index of i's component.
__global__ void k_labels(const int* __restrict__ gid, const int* __restrict__ compmin,
                         int* __restrict__ labels) {
    int i = blockIdx.x * blockDim.x + threadIdx.x;
    if (i >= N_PIX) return;
    labels[i] = compmin[gid[i]];
}

// K5: masks[c][n] = (labels[n] == c). 340 MB of float4 stores — the HBM-write
// roofline. Labels staged once per block in LDS (36 KB), 8 rows per block so
// global label traffic is ~41 MB total, hidden under the stores.
#define ROWS_PER_BLOCK 8
__global__ void __launch_bounds__(256) k_masks(const int* __restrict__ labels,
                                               float* __restrict__ out) {
    __shared__ int4 slab[N_PIX / 4];       // 36 KB
    const int4* l4 = (const int4*)labels;
    for (int idx = threadIdx.x; idx < N_PIX / 4; idx += 256) slab[idx] = l4[idx];
    __syncthreads();
    int c0 = blockIdx.x * ROWS_PER_BLOCK;
    for (int r = 0; r < ROWS_PER_BLOCK; ++r) {
        int c = c0 + r;
        float4* orow = (float4*)(out + (size_t)c * N_PIX);
        for (int idx = threadIdx.x; idx < N_PIX / 4; idx += 256) {
            int4 l = slab[idx];
            float4 o;
            o.x = (l.x == c) ? 1.0f : 0.0f;
            o.y = (l.y == c) ? 1.0f : 0.0f;
            o.z = (l.z == c) ? 1.0f : 0.0f;
            o.w = (l.w == c) ? 1.0f : 0.0f;
            orow[idx] = o;                 // 256 lanes x 16 B = 4 KB contiguous
        }
    }
}

extern "C" void kernel_launch(void* const* d_in, const int* in_sizes, int n_in,
                              void* d_out, int out_size, void* d_ws, size_t ws_size,
                              hipStream_t stream) {
    const float* spike = (const float*)d_in[0];
    const int* cs = (const int*)d_in[1];
    int T = in_sizes[0] / N_PIX;           // 64

    float* out = (float*)d_out;
    float* out_grid = out + (size_t)N_PIX * N_PIX;

    // workspace layout (~185 KB)
    float* v       = (float*)d_ws;
    float* gaps    = v + N_PIX;
    int*   ngaps   = (int*)(gaps + N_PIX);
    int*   gid     = ngaps + 4;
    int*   compmin = gid + N_PIX;
    int*   labels  = compmin + N_PIX;

    k_means <<<(N_PIX + 255) / 256, 256, 0, stream>>>(spike, cs, T, v, out_grid, compmin, ngaps);
    k_gaps  <<<N_PIX, 256, 0, stream>>>(v, gaps, ngaps);
    k_ids   <<<(N_PIX + 255) / 256, 256, 0, stream>>>(v, gaps, ngaps, gid, compmin);
    k_labels<<<(N_PIX + 255) / 256, 256, 0, stream>>>(gid, compmin, labels);
    k_masks <<<N_PIX / ROWS_PER_BLOCK, 256, 0, stream>>>(labels, out);
}

// Round 2
// 489.066 us; speedup vs baseline: 1.0347x; 1.0347x over previous
//
#include <hip/hip_runtime.h>

// MeanSpikeClassifier: interval-graph connected components.
// N = 96*96 = 9216 pixels, T = 64 steps, out = masks[N,N] ++ mean_grid[N] (f32).
//
// adj(i,j) = (1 - |v_i - v_j| >= 0.6) is an interval graph on the value line.
// Components = maximal value-runs not split by a "gap" (a value with no
// adjacent value above it). component_id(i) = #gap-start values < v_i.
// labels[i] = min pixel index in component (== reference while_loop fixpoint).
//
// masks is ultra-sparse: exactly N ones (pixel n lights row labels[n]).
// So: memset the 340 MB output to zero (runs at the device fill ceiling,
// ~6.2 TB/s measured on the harness's own fills) + a 9216-thread scatter.

#define N_PIX 9216

// K1: per-pixel mean of late steps; also init compmin/ngaps (ws is re-poisoned
// to 0xAA before every timed launch, so init must happen every call).
__global__ void k_means(const float* __restrict__ spike, const int* __restrict__ cs_p,
                        int T, float* __restrict__ v, float* __restrict__ out_grid,
                        int* __restrict__ compmin, int* __restrict__ ngaps) {
    int n = blockIdx.x * blockDim.x + threadIdx.x;
    if (n >= N_PIX) return;
    int cs = cs_p[0];
    int start = cs - 1;
    if (start < 0) start = 0;
    if (start > T - 1) start = T - 1;
    float s = 0.0f;
    for (int t = start; t < T; ++t)       // coalesced across n for each t
        s += spike[(size_t)t * N_PIX + n];
    float val = s / (float)(T - start);
    v[n] = val;
    out_grid[n] = val;
    compmin[n] = 0x7fffffff;
    if (n == 0) *ngaps = 0;
}

// K2: one block per pixel k — is k a "gap start"?
// gap(k) := (exists v_j > v_k) && (no j with v_j > v_k && 1-(v_j-v_k) >= 0.6f)
// Exact float predicate of the reference (monotone in the diff).
__global__ void __launch_bounds__(256) k_gaps(const float* __restrict__ v,
                                              float* __restrict__ gaps,
                                              int* __restrict__ ngaps) {
    int k = blockIdx.x;
    float vk = v[k];
    int hasG = 0, hasAdj = 0;
    for (int j = threadIdx.x; j < N_PIX; j += 256) {
        float vj = v[j];                   // 36 KB array, L1/L2-resident
        if (vj > vk) {
            hasG = 1;
            if (1.0f - (vj - vk) >= 0.6f) hasAdj = 1;
        }
    }
    __shared__ int sG, sA;
    if (threadIdx.x == 0) { sG = 0; sA = 0; }
    __syncthreads();
    if (hasG)   atomicOr(&sG, 1);
    if (hasAdj) atomicOr(&sA, 1);
    __syncthreads();
    if (threadIdx.x == 0 && sG && !sA) {
        int idx = atomicAdd(ngaps, 1);     // order-independent downstream
        gaps[idx] = vk;
    }
}

// K3: component id = #gap values strictly below v_i; per-component min index.
__global__ void k_ids(const float* __restrict__ v, const float* __restrict__ gaps,
                      const int* __restrict__ ngaps, int* __restrict__ gid,
                      int* __restrict__ compmin) {
    int i = blockIdx.x * blockDim.x + threadIdx.x;
    if (i >= N_PIX) return;
    float vi = v[i];
    int ng = *ngaps;                       // ~0-2 for this data
    int g = 0;
    for (int t = 0; t < ng; ++t) g += (gaps[t] < vi) ? 1 : 0;
    gid[i] = g;
    atomicMin(&compmin[g], i);
}

// K4: scatter the N ones into the zeroed mask: out[labels[n]*N + n] = 1.
// (In practice all labels are 0 -> fully coalesced row-0 write.)
__global__ void k_scatter(const int* __restrict__ gid, const int* __restrict__ compmin,
                          float* __restrict__ out) {
    int n = blockIdx.x * blockDim.x + threadIdx.x;
    if (n >= N_PIX) return;
    int label = compmin[gid[n]];
    out[(size_t)label * N_PIX + n] = 1.0f;
}

extern "C" void kernel_launch(void* const* d_in, const int* in_sizes, int n_in,
                              void* d_out, int out_size, void* d_ws, size_t ws_size,
                              hipStream_t stream) {
    const float* spike = (const float*)d_in[0];
    const int* cs = (const int*)d_in[1];
    int T = in_sizes[0] / N_PIX;           // 64

    float* out = (float*)d_out;
    float* out_grid = out + (size_t)N_PIX * N_PIX;

    // workspace layout (~150 KB)
    float* v       = (float*)d_ws;
    float* gaps    = v + N_PIX;
    int*   ngaps   = (int*)(gaps + N_PIX);
    int*   gid     = ngaps + 4;
    int*   compmin = gid + N_PIX;

    // Zero the 340 MB mask region at the device fill ceiling; overlaps nothing
    // (out_grid lives beyond N*N and is written by k_means).
    hipMemsetAsync(out, 0, (size_t)N_PIX * N_PIX * sizeof(float), stream);

    k_means  <<<(N_PIX + 255) / 256, 256, 0, stream>>>(spike, cs, T, v, out_grid, compmin, ngaps);
    k_gaps   <<<N_PIX, 256, 0, stream>>>(v, gaps, ngaps);
    k_ids    <<<(N_PIX + 255) / 256, 256, 0, stream>>>(v, gaps, ngaps, gid, compmin);
    k_scatter<<<(N_PIX + 255) / 256, 256, 0, stream>>>(gid, compmin, out);
}